// Round 6
// baseline (176.216 us; speedup 1.0000x reference)
//
#include <hip/hip_runtime.h>

// ---------------- types / helpers ----------------
typedef unsigned short u16;
typedef float f32x4 __attribute__((ext_vector_type(4)));
typedef short bf16x8 __attribute__((ext_vector_type(8)));
typedef short bf16x4 __attribute__((ext_vector_type(4)));

__device__ __forceinline__ u16 f2bf(float f) {
    unsigned u = __float_as_uint(f);
    u = (u + 0x7FFFu + ((u >> 16) & 1u)) >> 16;
    return (u16)u;
}

#define LOG2E 1.4426950408889634f

#if __has_builtin(__builtin_amdgcn_exp2f)
__device__ __forceinline__ float exp2_fast(float x) { return __builtin_amdgcn_exp2f(x); }
#else
__device__ __forceinline__ float exp2_fast(float x) { return __expf(x * 0.6931471805599453f); }
#endif

// pack two fp32 -> (bf16(b)<<16)|bf16(a), round-half-up
__device__ __forceinline__ unsigned pack2bf(float a, float b) {
    unsigned ua = __float_as_uint(a) + 0x8000u;
    unsigned ub = __float_as_uint(b) + 0x8000u;
#if __has_builtin(__builtin_amdgcn_perm)
    return __builtin_amdgcn_perm(ub, ua, 0x07060302u);
#else
    return ((ua >> 16) & 0xFFFFu) | (ub & 0xFFFF0000u);
#endif
}

__device__ __forceinline__ bf16x4 bc4(uint2 u) { return __builtin_bit_cast(bf16x4, u); }
__device__ __forceinline__ bf16x8 bc8(uint4 u) { return __builtin_bit_cast(bf16x8, u); }

// PV MFMA: 16x16x16 bf16 (K=16). A[m=lane&15][k=quad*4+j], B[k=quad*4+j][n=lane&15].
#if __has_builtin(__builtin_amdgcn_mfma_f32_16x16x16bf16_1k)
__device__ __forceinline__ f32x4 pv_mfma(bf16x4 a, bf16x4 b, f32x4 c) {
    return __builtin_amdgcn_mfma_f32_16x16x16bf16_1k(a, b, c, 0, 0, 0);
}
#elif __has_builtin(__builtin_amdgcn_mfma_f32_16x16x16_bf16)
__device__ __forceinline__ f32x4 pv_mfma(bf16x4 a, bf16x4 b, f32x4 c) {
    return __builtin_amdgcn_mfma_f32_16x16x16_bf16(a, b, c, 0, 0, 0);
}
#else
// Exact fallback: 16x16x32 with zero-padded high halves.
__device__ __forceinline__ f32x4 pv_mfma(bf16x4 a, bf16x4 b, f32x4 c) {
    bf16x8 a8 = {a[0], a[1], a[2], a[3], 0, 0, 0, 0};
    bf16x8 b8 = {b[0], b[1], b[2], b[3], 0, 0, 0, 0};
    return __builtin_amdgcn_mfma_f32_16x16x32_bf16(a8, b8, c, 0, 0, 0);
}
#endif

// Problem constants
#define BB 2
#define HH 56
#define CC 256
#define NH 8
#define DK 32
#define SQ 3136          // 56*56
#define HP 62
#define SK 3844          // 62*62
#define VT_STRIDE 3856   // padded row stride for Vt (16B-aligned rows)

// workspace offsets (u16 units); total 5,844,992 u16 = 11.7 MB (proven-safe < 15.4 MB)
#define WS_WT   0         // 3*65536
#define WS_Q    196608    // 6272*256
#define WS_K    1802240   // 7688*256
#define WS_VT   3770368   // 512*3856
#define WS_LB   5744640   // 50176 floats (l sums) = 100352 u16

#define NZERO_F4 413952   // (6272*256 + 6272*8)/4 floats -> float4 count

// ---------------- kernel 0: transpose weights + zero out/lbuf ----------------
// mat 0 (Wq) pre-scaled by log2(e) so attention scores land in log2 domain.
__global__ __launch_bounds__(256) void wtrans_kernel(const float* __restrict__ Wq,
                                                     const float* __restrict__ Wk,
                                                     const float* __restrict__ Wv,
                                                     u16* __restrict__ wt,
                                                     float* __restrict__ out,
                                                     float* __restrict__ lbuf) {
    int gid = blockIdx.x * 256 + threadIdx.x;     // 768*256 = 196608 threads
    int mat = gid >> 16;
    int rem = gid & 65535;
    int k = rem >> 8;
    int n = rem & 255;
    const float* W = (mat == 0) ? Wq : ((mat == 1) ? Wk : Wv);
    float val = W[(k << 8) + n];
    if (mat == 0) val *= LOG2E;
    wt[(mat << 16) + (n << 8) + k] = f2bf(val);

    // grid-stride zero of out (1,605,632 f) then lbuf (50,176 f), as float4
    const int n_out4 = (SQ * BB * CC) / 4;        // 401408
    for (int i = gid; i < NZERO_F4; i += 196608) {
        if (i < n_out4) *(float4*)&out[i * 4] = (float4){0.f, 0.f, 0.f, 0.f};
        else            *(float4*)&lbuf[(i - n_out4) * 4] = (float4){0.f, 0.f, 0.f, 0.f};
    }
}

// ---------------- kernel 1: projections, reflect-pad folded in, N split in 2 ----------------
// grid (121, 3 modes, 2 n-halves). mode: 0=Q (M=6272), 1=K, 2=V-transposed (M=7688).
#define BSTR 40
__global__ __launch_bounds__(256, 4) void proj_kernel(const float* __restrict__ x,
                                                      const u16* __restrict__ wt,
                                                      const float* __restrict__ bq,
                                                      const float* __restrict__ bk,
                                                      const float* __restrict__ bv,
                                                      u16* __restrict__ qout,
                                                      u16* __restrict__ kout,
                                                      u16* __restrict__ vtout) {
    __shared__ __align__(16) u16 Bl[128 * BSTR];

    int mode  = blockIdx.y;
    int nz    = blockIdx.z;
    int mbase = blockIdx.x * 64;
    int M = (mode == 0) ? (BB * SQ) : (BB * SK);
    if (mbase >= M) return;
    int tid = threadIdx.x;
    int wave = tid >> 6, lane = tid & 63, quad = lane >> 4, l16 = lane & 15;

    int m_a = mbase + wave * 16 + l16;           // A-fragment row
    if (m_a >= M) m_a = M - 1;
    int xrow;
    if (mode == 0) {
        xrow = m_a;                              // Q: interior rows are x rows directly
    } else {
        int b = (m_a >= SK) ? 1 : 0;
        int sp = m_a - b * SK;
        int hp = sp / HP, wp = sp - hp * HP;
        int hs = hp - 3; hs = hs < 0 ? -hs : (hs >= HH ? 110 - hs : hs);
        int ws_ = wp - 3; ws_ = ws_ < 0 ? -ws_ : (ws_ >= HH ? 110 - ws_ : ws_);
        xrow = b * SQ + hs * HH + ws_;
    }
    const float* xr = x + (size_t)xrow * 256;
    const u16* wmat = wt + (mode << 16);
    const float* bias = (mode == 0) ? bq : ((mode == 1) ? bk : bv);
    float bscale = (mode == 0) ? LOG2E : 1.0f;

    f32x4 acc[8];
#pragma unroll
    for (int i = 0; i < 8; i++) acc[i] = (f32x4){0.f, 0.f, 0.f, 0.f};

    uint4 breg[2];
    auto bload = [&](int kk) {
#pragma unroll
        for (int i = 0; i < 2; i++) {
            int j = i * 256 + tid;
            int rrow = j >> 2, part = j & 3;
            breg[i] = *(const uint4*)&wmat[((nz * 128 + rrow) << 8) + kk + part * 8];
        }
    };

    bload(0);
    for (int s = 0; s < 8; ++s) {
        int kk = s * 32;
#pragma unroll
        for (int i = 0; i < 2; i++) {
            int j = i * 256 + tid;
            int rrow = j >> 2, part = j & 3;
            *(uint4*)&Bl[rrow * BSTR + part * 8] = breg[i];
        }
        __syncthreads();
        if (s < 7) bload(kk + 32);
        // A-frag: 8 contiguous fp32 channels -> bf16x8 in registers
        float4 f0 = *(const float4*)&xr[kk + quad * 8];
        float4 f1 = *(const float4*)&xr[kk + quad * 8 + 4];
        uint4 aw = (uint4){pack2bf(f0.x, f0.y), pack2bf(f0.z, f0.w),
                           pack2bf(f1.x, f1.y), pack2bf(f1.z, f1.w)};
        bf16x8 afrag = bc8(aw);
#pragma unroll
        for (int nt = 0; nt < 8; nt++) {
            bf16x8 bfrag = *(const bf16x8*)&Bl[(nt * 16 + l16) * BSTR + quad * 8];
            acc[nt] = __builtin_amdgcn_mfma_f32_16x16x32_bf16(afrag, bfrag, acc[nt], 0, 0, 0);
        }
        __syncthreads();
    }

    // epilogue: C/D layout row = quad*4+reg, col = lane&15
    int mrow_base = mbase + wave * 16 + quad * 4;
    if (mode == 2) {
#pragma unroll
        for (int nt = 0; nt < 8; nt++) {
            int c = nz * 128 + nt * 16 + l16;
            float bvv = bias[c];
#pragma unroll
            for (int p = 0; p < 4; p += 2) {
                int m = mrow_base + p;
                if (m + 1 < M) {
                    int bb = (m >= SK) ? 1 : 0;
                    int kp = m - bb * SK;
                    unsigned pk = pack2bf(acc[nt][p] + bvv, acc[nt][p + 1] + bvv);
                    *(unsigned*)&vtout[(size_t)(bb * 256 + c) * VT_STRIDE + kp] = pk;
                }
            }
        }
    } else {
#pragma unroll
        for (int r = 0; r < 4; r++) {
            int m = mrow_base + r;
            if (m >= M) continue;
#pragma unroll
            for (int nt = 0; nt < 8; nt++) {
                int c = nz * 128 + nt * 16 + l16;
                float v = acc[nt][r] + bias[c] * bscale;
                u16 hv = f2bf(v);
                if (mode == 0) qout[((size_t)m << 8) + c] = hv;
                else           kout[((size_t)m << 8) + c] = hv;
            }
        }
    }
}

// ---------------- kernel 2: flash attention (fixed m=0), keys split across blocks ----------------
// grid (49 q-tiles, 16 b*h, 2 key-halves), 256 thr = 4 waves; wave owns 16 queries.
// Partial O accumulated into out via fp32 atomicAdd (exactly 2 contributors/elem -> deterministic);
// partial l into lbuf. finalize_kernel divides and adds residual.
#define KSTR 40
#define VSTR 136
__global__ __launch_bounds__(256, 6) void attn_kernel(const u16* __restrict__ qb,
                                                      const u16* __restrict__ kb,
                                                      const u16* __restrict__ vtb,
                                                      float* __restrict__ out,
                                                      float* __restrict__ lbuf) {
    __shared__ __align__(16) u16 K_lds[128 * KSTR];   // 128 keys x 32 dk
    __shared__ __align__(16) u16 V_lds[32 * VSTR];    // 32 dk x 128 keys

    int tid = threadIdx.x;
    int wave = tid >> 6, lane = tid & 63, quad = lane >> 4, l16 = lane & 15;
    int bh = blockIdx.y;
    int b = bh >> 3, h = bh & 7;
    int half = blockIdx.z;
    int qsub = blockIdx.x * 64 + wave * 16;
    int rounds = (half == 0) ? 16 : 15;               // 31 chunks total

    // Q B-fragment (16x16x32): n = l16 -> query, k = quad*8+j
    bf16x8 qf = *(const bf16x8*)&qb[((size_t)(b * SQ + qsub + l16) << 8) + h * 32 + quad * 8];

    const u16* kg = kb + ((size_t)(b * SK) << 8) + h * 32;
    const u16* vg = vtb + (size_t)(b * 256 + h * 32) * VT_STRIDE;

    int srow = tid >> 2, spart = tid & 3;   // K staging: rows srow, srow+64
    int sdu  = tid >> 4, sc16  = tid & 15;  // V staging: rows sdu, sdu+16

    f32x4 o0{0.f,0.f,0.f,0.f}, o1{0.f,0.f,0.f,0.f}, lv{0.f,0.f,0.f,0.f};

    // ones B-frag (16x16x16): B[k][n=0]=1 -> lanes with l16==0 hold ones
    short ov = (l16 == 0) ? (short)0x3F80 : (short)0;
    bf16x4 ones4 = {ov, ov, ov, ov};

    uint4 kr0, kr1, vr0, vr1;
    auto prefetch = [&](int rr) {
        int ka = (half * 16 + rr) * 128;
        int g;
        g = ka + srow;        if (g > SK - 1) g = SK - 1;
        kr0 = *(const uint4*)&kg[((size_t)g << 8) + spart * 8];
        g = ka + srow + 64;   if (g > SK - 1) g = SK - 1;
        kr1 = *(const uint4*)&kg[((size_t)g << 8) + spart * 8];
        int c = ka + sc16 * 8;  if (c > VT_STRIDE - 8) c = VT_STRIDE - 8;
        vr0 = *(const uint4*)&vg[(size_t)sdu * VT_STRIDE + c];
        vr1 = *(const uint4*)&vg[(size_t)(sdu + 16) * VT_STRIDE + c];
    };
    auto writeAll = [&]() {
        *(uint4*)&K_lds[srow * KSTR + spart * 8] = kr0;
        *(uint4*)&K_lds[(srow + 64) * KSTR + spart * 8] = kr1;
        *(uint4*)&V_lds[sdu * VSTR + sc16 * 8] = vr0;
        *(uint4*)&V_lds[(sdu + 16) * VSTR + sc16 * 8] = vr1;
    };

    prefetch(0);
    writeAll();
    __syncthreads();
    prefetch(1);

    for (int r = 0; r < rounds; ++r) {
        int ch = half * 16 + r;
        bool tail = (ch == 30);
#pragma unroll
        for (int t = 0; t < 8; ++t) {
            bf16x8 kf = *(const bf16x8*)&K_lds[(t * 16 + l16) * KSTR + quad * 8];
            f32x4 e0 = __builtin_amdgcn_mfma_f32_16x16x32_bf16(kf, qf, (f32x4){0.f,0.f,0.f,0.f}, 0, 0, 0);
            float p0[4];
            if (tail) {
                int kb0 = ch * 128 + t * 16 + quad * 4;
#pragma unroll
                for (int j = 0; j < 4; ++j)
                    p0[j] = ((kb0 + j) < SK) ? exp2_fast(e0[j]) : 0.f;
            } else {
#pragma unroll
                for (int j = 0; j < 4; ++j) p0[j] = exp2_fast(e0[j]);
            }
            uint2 u0 = (uint2){pack2bf(p0[0], p0[1]), pack2bf(p0[2], p0[3])};
            bf16x4 pa = bc4(u0);
            uint2 w0 = *(const uint2*)&V_lds[l16 * VSTR + t * 16 + quad * 4];
            uint2 w1 = *(const uint2*)&V_lds[(16 + l16) * VSTR + t * 16 + quad * 4];
            o0 = pv_mfma(pa, bc4(w0), o0);
            o1 = pv_mfma(pa, bc4(w1), o1);
            lv = pv_mfma(pa, ones4, lv);
        }
        __syncthreads();                 // all reads of this round done
        if (r < rounds - 1) writeAll();  // write next round's chunk
        __syncthreads();                 // writes visible
        if (r < rounds - 2) prefetch(r + 2);
    }

    // ---- epilogue: accumulate partials (device-scope fp32 atomics) ----
#pragma unroll
    for (int r2 = 0; r2 < 4; ++r2) {
        int q = qsub + quad * 4 + r2;
        size_t base = (size_t)(b * SQ + q) * 256 + h * 32;
        atomicAdd(&out[base + l16],      o0[r2]);
        atomicAdd(&out[base + 16 + l16], o1[r2]);
        if (l16 == 0) atomicAdd(&lbuf[(b * SQ + q) * 8 + h], lv[r2]);
    }
}

// ---------------- kernel 3: finalize out = gamma * O / l + x ----------------
__global__ __launch_bounds__(256) void finalize_kernel(const float* __restrict__ x,
                                                       const float* __restrict__ gammap,
                                                       const float* __restrict__ lbuf,
                                                       float* __restrict__ out) {
    int gid = blockIdx.x * 256 + threadIdx.x;   // 6272*64 threads, float4 each
    int row = gid >> 6;
    int c4  = (gid & 63) << 2;
    int h   = c4 >> 5;
    float g = gammap[0];
    float linv = g / lbuf[row * 8 + h];
    size_t base = (size_t)row * 256 + c4;
    float4 o = *(const float4*)&out[base];
    float4 xv = *(const float4*)&x[base];
    o.x = o.x * linv + xv.x;
    o.y = o.y * linv + xv.y;
    o.z = o.z * linv + xv.z;
    o.w = o.w * linv + xv.w;
    *(float4*)&out[base] = o;
}

// ---------------- launcher ----------------
extern "C" void kernel_launch(void* const* d_in, const int* in_sizes, int n_in,
                              void* d_out, int out_size, void* d_ws, size_t ws_size,
                              hipStream_t stream) {
    const float* x     = (const float*)d_in[0];
    const float* Wq    = (const float*)d_in[1];
    const float* bq    = (const float*)d_in[2];
    const float* Wk    = (const float*)d_in[3];
    const float* bk    = (const float*)d_in[4];
    const float* Wv    = (const float*)d_in[5];
    const float* bv    = (const float*)d_in[6];
    const float* gamma = (const float*)d_in[7];
    float* out = (float*)d_out;

    u16* ws   = (u16*)d_ws;
    u16* wt   = ws + WS_WT;
    u16* qbuf = ws + WS_Q;
    u16* kbuf = ws + WS_K;
    u16* vtb  = ws + WS_VT;
    float* lbuf = (float*)(ws + WS_LB);

    wtrans_kernel<<<768, 256, 0, stream>>>(Wq, Wk, Wv, wt, out, lbuf);
    proj_kernel<<<dim3(121, 3, 2), 256, 0, stream>>>(x, wt, bq, bk, bv, qbuf, kbuf, vtb);
    attn_kernel<<<dim3(49, 16, 2), 256, 0, stream>>>(qbuf, kbuf, vtb, out, lbuf);
    finalize_kernel<<<1568, 256, 0, stream>>>(x, gamma, lbuf, out);
}